// Round 6
// baseline (508.233 us; speedup 1.0000x reference)
//
#include <hip/hip_runtime.h>
#include <hip/hip_bf16.h>

typedef unsigned short u16;
typedef unsigned int   u32;

#define N_   32
#define T_   32
#define V_   128
#define CIN_ 264
#define CO_  64
#define KT_  9
#define EPS_ 1e-3f

// ---- param table (float offsets inside ws) ----
#define OFF_DBN_S 0          // 33792
#define OFF_DBN_O 33792      // 33792
#define OFF_W0    67584      // 264*64 (f32 copy, unused by mfma path; harmless)
#define OFF_BW0   84480      // 64
#define OFF_A0S   84544
#define OFF_A0O   84608
#define OFF_B0S   84672      // includes bt0 fold
#define OFF_B0O   84736
#define OFF_W1    84800      // 64*64 f32 (pw1)
#define OFF_BW1   88896
#define OFF_A1S   88960
#define OFF_A1O   89024
#define OFF_B1S   89088      // includes bt1 fold
#define OFF_B1O   89152
#define PREP_TOTAL 110464    // + W0A (64*288) + WTA (9*64*64)

// ---- ws byte layout ----
#define B_P    0
#define B_FLAG 360448
#define B_W0A  360512                    // bf16 64 x 288  (36864 B)
#define B_WTA  397440                    // bf16 9 x 64 x 64 (73728 B)
#define B_H0   524288                    // bf16 [n][c][t][v]  16 MB
#define B_G0   (B_H0 + 16777216)         // bf16 [n][t][v][i]  16 MB
#define B_L0   (B_G0 + 16777216)         // f32  [n][c][t][v]  32 MB
#define B_G1P  (B_L0 + 33554432)         // f32  [n][c][t]     256 KB
#define B_XP2  (B_G1P + 262144)          // bf16 [n][4096][264]  69.2 MB
#define B_END  (B_XP2 + 69206016)        // ~137 MB (guarded)

typedef short bf16x8 __attribute__((ext_vector_type(8)));
typedef float f32x4  __attribute__((ext_vector_type(4)));

__device__ __forceinline__ float bf2f(u16 u) { return __uint_as_float(((u32)u) << 16); }
__device__ __forceinline__ u16 f2bf(float f) {
    u32 x = __float_as_uint(f);
    return (u16)((x + 0x7fffu + ((x >> 16) & 1u)) >> 16);
}
__device__ __forceinline__ float ldin(const void* p, u32 i, int f32) {
    return f32 ? ((const float*)p)[i] : bf2f(((const u16*)p)[i]);
}
// LDS transpose swizzle for graph0 (see k_graph0)
__device__ __forceinline__ u32 swzv(u32 v) {
    u32 m = (v >> 3) & 7u;
    return (m << 4) ^ ((m & 3u) << 5);
}

// ---------------- dtype detect (bf16 vs f32 input buffers) ----------------
__global__ void k_detect(const void* a, int* flag) {
    if (threadIdx.x == 0 && blockIdx.x == 0) {
        const u16* p = (const u16*)a;
        int cnt = 0;
        for (int i = 0; i < 64; ++i) {
            float v = bf2f(p[2 * i]);
            if (v >= 0.f && v <= 1.0f) ++cnt;
        }
        *flag = (cnt >= 56) ? 0 : 1;
    }
}

// ---------------- param prep: BN folds + bf16 MFMA weight layouts ----------------
__global__ void k_prep(const void* dbn_g, const void* dbn_b, const void* dbn_m, const void* dbn_v,
                       const void* w0, const void* bw0,
                       const void* g0a, const void* b0a, const void* m0a, const void* v0a,
                       const void* bt0, const void* g0b, const void* b0b, const void* m0b, const void* v0b,
                       const void* w1, const void* bw1,
                       const void* g1a, const void* b1a, const void* m1a, const void* v1a,
                       const void* bt1, const void* g1b, const void* b1b, const void* m1b, const void* v1b,
                       const void* wt0,
                       float* P, u16* W0A, u16* WTA, const int* flagp)
{
    const int f32 = *flagp;
    int i = blockIdx.x * 256 + threadIdx.x;
    if (i < 33792) {
        float s = ldin(dbn_g, i, f32) * rsqrtf(ldin(dbn_v, i, f32) + EPS_);
        P[OFF_DBN_S + i] = s;
        P[OFF_DBN_O + i] = ldin(dbn_b, i, f32) - ldin(dbn_m, i, f32) * s;
    } else if (i < 50688) { int j = i - 33792; P[OFF_W0 + j] = ldin(w0, j, f32); }
    else if (i < 50752) { int j = i - 50688; P[OFF_BW0 + j] = ldin(bw0, j, f32); }
    else if (i < 50816) { int j = i - 50752;
        float s = ldin(g0a, j, f32) * rsqrtf(ldin(v0a, j, f32) + EPS_);
        P[OFF_A0S + j] = s; P[OFF_A0O + j] = ldin(b0a, j, f32) - ldin(m0a, j, f32) * s;
    } else if (i < 50880) { int j = i - 50816;
        float s = ldin(g0b, j, f32) * rsqrtf(ldin(v0b, j, f32) + EPS_);
        P[OFF_B0S + j] = s; P[OFF_B0O + j] = (ldin(bt0, j, f32) - ldin(m0b, j, f32)) * s + ldin(b0b, j, f32);
    } else if (i < 54976) { int j = i - 50880; P[OFF_W1 + j] = ldin(w1, j, f32); }
    else if (i < 55040) { int j = i - 54976; P[OFF_BW1 + j] = ldin(bw1, j, f32); }
    else if (i < 55104) { int j = i - 55040;
        float s = ldin(g1a, j, f32) * rsqrtf(ldin(v1a, j, f32) + EPS_);
        P[OFF_A1S + j] = s; P[OFF_A1O + j] = ldin(b1a, j, f32) - ldin(m1a, j, f32) * s;
    } else if (i < 55168) { int j = i - 55104;
        float s = ldin(g1b, j, f32) * rsqrtf(ldin(v1b, j, f32) + EPS_);
        P[OFF_B1S + j] = s; P[OFF_B1O + j] = (ldin(bt1, j, f32) - ldin(m1b, j, f32)) * s + ldin(b1b, j, f32);
    } else if (i < 73600) {      // W0A[c][288]: w0^T, row 264 = bw0 (bias trick), 265.. = 0
        int j = i - 55168; int c = j / 288, ci = j - c * 288;
        float val = (ci < 264) ? ldin(w0, (u32)ci * 64 + c, f32)
                  : ((ci == 264) ? ldin(bw0, c, f32) : 0.f);
        W0A[j] = f2bf(val);
    } else if (i < 110464) {     // WTA[k][o][i] = wt0[k][0][i][o]
        int j = i - 73600; int k = j >> 12, rem = j & 4095, o = rem >> 6, ii = rem & 63;
        WTA[j] = f2bf(ldin(wt0, ((u32)(k * 64 + ii)) * 64 + o, f32));
    }
}

// ---------------- BN + concat + permute: src[n][ts][vs][cc] -> Xp[n][t2*128+vv][c2] bf16 ----------------
// ILP-restructured phase 1: all NQ src loads issued, then all P loads, then compute+LDS write.
// (Round-4 version had VGPR=12 -> one outstanding load per thread -> 1.9 TB/s latency-bound.)
template<int NQ>
__device__ __forceinline__ void bnx_p1(const void* __restrict__ xin, const void* __restrict__ bin,
                                       const void* __restrict__ cin2, const float* __restrict__ P,
                                       u16* tile, int f32, int n, int c0, int r0, int tid)
{
    u32 chv[NQ];
    int jv[NQ], i4v[NQ];
    float4 val[NQ];
    ushort4 raw[NQ];

    // --- address calc + src loads (independent, all in flight) ---
#pragma unroll
    for (int it = 0; it < NQ; ++it) {
        int q = it * 256 + tid;
        int j = q >> 5, i4 = (q & 31) << 2;
        jv[it] = j; i4v[it] = i4;
        u32 L = (u32)(c0 + j) * 4096u + (u32)(r0 + i4);
        u32 vs = L / 8448u;
        u32 r  = L - vs * 8448u;
        u32 ts = r / 264u;
        u32 cc = r - ts * 264u;                    // multiple of 4; chunk never crosses segment bounds
        u32 base = ((u32)n * 32u + ts) * 128u + vs;
        chv[it] = vs * 264u + cc;
        if (f32) {
            if (cc < 256u)      val[it] = *(const float4*)((const float*)xin  + (size_t)base * 256u + cc);
            else if (cc < 260u) val[it] = *(const float4*)((const float*)bin  + (size_t)base * 4u + (cc - 256u));
            else                val[it] = *(const float4*)((const float*)cin2 + (size_t)base * 4u + (cc - 260u));
        } else {
            if (cc < 256u)      raw[it] = *(const ushort4*)((const u16*)xin  + (size_t)base * 256u + cc);
            else if (cc < 260u) raw[it] = *(const ushort4*)((const u16*)bin  + (size_t)base * 4u + (cc - 256u));
            else                raw[it] = *(const ushort4*)((const u16*)cin2 + (size_t)base * 4u + (cc - 260u));
        }
    }
    // --- P loads (independent of src-load results) ---
    float4 s4[NQ], o4[NQ];
#pragma unroll
    for (int it = 0; it < NQ; ++it) {
        s4[it] = *(const float4*)&P[OFF_DBN_S + chv[it]];
        o4[it] = *(const float4*)&P[OFF_DBN_O + chv[it]];
    }
    // --- convert + BN + pack + LDS write ---
#pragma unroll
    for (int it = 0; it < NQ; ++it) {
        float4 v = val[it];
        if (!f32) { v.x = bf2f(raw[it].x); v.y = bf2f(raw[it].y); v.z = bf2f(raw[it].z); v.w = bf2f(raw[it].w); }
        ushort2 lo, hi;
        lo.x = f2bf(fmaf(v.x, s4[it].x, o4[it].x));
        lo.y = f2bf(fmaf(v.y, s4[it].y, o4[it].y));
        hi.x = f2bf(fmaf(v.z, s4[it].z, o4[it].z));
        hi.y = f2bf(fmaf(v.w, s4[it].w, o4[it].w));
        *(ushort2*)&tile[jv[it] * 130 + i4v[it]]     = lo;
        *(ushort2*)&tile[jv[it] * 130 + i4v[it] + 2] = hi;
    }
}

__global__ __launch_bounds__(256) void k_bnx(const void* __restrict__ xin, const void* __restrict__ bin,
                                             const void* __restrict__ cin2, const float* __restrict__ P,
                                             u16* __restrict__ Xp, const int* __restrict__ flagp)
{
    __shared__ __align__(16) u16 tile[32 * 130];
    const int f32 = *flagp;
    const int rt = blockIdx.x;           // 0..31  -> rows r0..r0+127
    const int ct = blockIdx.y;           // 0..8   -> cols c0..c0+ncols-1
    const int n  = blockIdx.z;           // 0..31
    const int c0 = ct * 32;
    const int ncols = (ct == 8) ? 8 : 32;
    const int r0 = rt * 128;
    const int tid = threadIdx.x;

    if (ncols == 32) bnx_p1<4>(xin, bin, cin2, P, tile, f32, n, c0, r0, tid);
    else             bnx_p1<1>(xin, bin, cin2, P, tile, f32, n, c0, r0, tid);
    __syncthreads();

    const int chunks = ncols >> 3;                 // 4 or 1
    for (int e = tid; e < 128 * chunks; e += 256) {
        int i, cch;
        if (chunks == 4) { i = e >> 2; cch = e & 3; } else { i = e; cch = 0; }
        __align__(16) u16 tmp[8];
#pragma unroll
        for (int k2 = 0; k2 < 8; ++k2) tmp[k2] = tile[(cch * 8 + k2) * 130 + i];
        *(uint4*)&Xp[((u32)n * 4096u + (u32)(r0 + i)) * 264u + (u32)(c0 + cch * 8)] = *(uint4*)tmp;
    }
}

// ---------------- MFMA pw0: D[v][c] = Xp-row . W0A^T. No LDS; a-frags straight from Xp (K-contiguous). ----------------
__global__ __launch_bounds__(256) void k_pw0(const u16* __restrict__ Xp, const u16* __restrict__ W0Ag,
                                             u16* __restrict__ h0)
{
    const int t2 = blockIdx.x, n = blockIdx.y, vh = blockIdx.z;
    const int tid = threadIdx.x;
    const int wv = tid >> 6, lane = tid & 63, l16 = lane & 15, quad = lane >> 4;
    const int m0 = wv * 16;
    const int vrow = vh * 64 + m0 + l16;
    const u16* arow = Xp + ((u32)n * 4096u + (u32)(t2 * 128 + vrow)) * 264u;

    f32x4 acc[4];
#pragma unroll
    for (int i = 0; i < 4; ++i) acc[i] = (f32x4){0.f, 0.f, 0.f, 0.f};

#pragma unroll
    for (int ks = 0; ks < 8; ++ks) {               // k = 0..255
        const int k0 = ks * 32 + quad * 8;
        bf16x8 af = *(const bf16x8*)&arow[k0];
#pragma unroll
        for (int ni = 0; ni < 4; ++ni) {
            bf16x8 bf = *(const bf16x8*)&W0Ag[(u32)(ni * 16 + l16) * 288 + k0];
            acc[ni] = __builtin_amdgcn_mfma_f32_16x16x32_bf16(af, bf, acc[ni], 0, 0, 0);
        }
    }
    {                                              // tail: k = 256..287 (264 real + bias@264 + zeros)
        bf16x8 af = (bf16x8){0, 0, 0, 0, 0, 0, 0, 0};
        if (quad == 0)      af = *(const bf16x8*)&arow[256];
        else if (quad == 1) af[0] = (short)0x3F80; // bf16 1.0 -> picks up bw0 row of W0A
        const int k0 = 256 + quad * 8;
#pragma unroll
        for (int ni = 0; ni < 4; ++ni) {
            bf16x8 bf = *(const bf16x8*)&W0Ag[(u32)(ni * 16 + l16) * 288 + k0];
            acc[ni] = __builtin_amdgcn_mfma_f32_16x16x32_bf16(af, bf, acc[ni], 0, 0, 0);
        }
    }
    const int v = vh * 64 + m0 + quad * 4;
#pragma unroll
    for (int ni = 0; ni < 4; ++ni) {
        int c = ni * 16 + l16;
        ushort4 rr; u16* rp = (u16*)&rr;
#pragma unroll
        for (int r = 0; r < 4; ++r) rp[r] = f2bf(acc[ni][r]);
        *(ushort4*)&h0[((u32)(n * 64 + c) * 32 + t2) * 128 + v] = rr;
    }
}

// ---------------- MFMA graph0, FUSED a*imp transpose + BN0a + PReLU -> g0[n][t][v][i] ----------------
__global__ __launch_bounds__(256) void k_graph0(const void* __restrict__ a, const void* __restrict__ imp0,
                                                const void* __restrict__ al0, const float* __restrict__ P,
                                                const u16* __restrict__ h0, u16* __restrict__ g0,
                                                const int* __restrict__ flagp)
{
    __shared__ __align__(16) u16 tile[128 * 128];  // 32 KB, [v][w] with byte ^= swzv(v)
    const int f32 = *flagp;
    const int t = blockIdx.x, n = blockIdx.y;
    const int tid = threadIdx.x;
    const u32 abase = (((u32)n * 32u + (u32)t) * 128u) * 128u;

    for (int e = tid; e < 2048; e += 256) {
        int v = e >> 4, w0 = (e & 15) << 3;
        float vals[8];
        if (f32) {
            const float* ap = (const float*)a + abase + (u32)v * 128u + w0;
            const float* ip = (const float*)imp0 + (u32)v * 128u + w0;
            float4 x0 = *(const float4*)ap, x1 = *(const float4*)(ap + 4);
            float4 i0 = *(const float4*)ip, i1 = *(const float4*)(ip + 4);
            vals[0] = x0.x * i0.x; vals[1] = x0.y * i0.y; vals[2] = x0.z * i0.z; vals[3] = x0.w * i0.w;
            vals[4] = x1.x * i1.x; vals[5] = x1.y * i1.y; vals[6] = x1.z * i1.z; vals[7] = x1.w * i1.w;
        } else {
            uint4 xu = *(const uint4*)((const u16*)a + abase + (u32)v * 128u + w0);
            uint4 iu = *(const uint4*)((const u16*)imp0 + (u32)v * 128u + w0);
            const u16* xp = (const u16*)&xu; const u16* ip = (const u16*)&iu;
#pragma unroll
            for (int j = 0; j < 8; ++j) vals[j] = bf2f(xp[j]) * bf2f(ip[j]);
        }
        __align__(16) u16 pk[8];
#pragma unroll
        for (int j = 0; j < 8; ++j) pk[j] = f2bf(vals[j]);
        u32 byte = (u32)v * 256u + (((u32)w0 * 2u) ^ swzv((u32)v));
        *(uint4*)((char*)tile + byte) = *(uint4*)pk;
    }
    __syncthreads();

    const int wv = tid >> 6, lane = tid & 63, l16 = lane & 15, quad = lane >> 4;
    const int n0w = wv * 32;
    const u16* Hb = h0 + ((u32)n * 2048u + (u32)t) * 128u;          // + c*4096 + v

    f32x4 acc[4][2];
#pragma unroll
    for (int mi = 0; mi < 4; ++mi) { acc[mi][0] = (f32x4){0,0,0,0}; acc[mi][1] = (f32x4){0,0,0,0}; }
#pragma unroll
    for (int ks = 0; ks < 4; ++ks) {
        const int k0 = ks * 32 + quad * 8;
        const u32 xr = swzv((u32)k0);
        const u32 wb0 = (u32)(n0w + l16) * 2u;
        const u32 wb1 = (u32)(n0w + 16 + l16) * 2u;
        bf16x8 bf0, bf1;
#pragma unroll
        for (int j = 0; j < 8; ++j) {
            const u32 rb = (u32)(k0 + j) * 256u;
            bf0[j] = (short)*(const u16*)((const char*)tile + rb + (wb0 ^ xr));
            bf1[j] = (short)*(const u16*)((const char*)tile + rb + (wb1 ^ xr));
        }
#pragma unroll
        for (int mi = 0; mi < 4; ++mi) {
            bf16x8 af = *(const bf16x8*)&Hb[(u32)(mi * 16 + l16) * 4096u + k0];
            acc[mi][0] = __builtin_amdgcn_mfma_f32_16x16x32_bf16(af, bf0, acc[mi][0], 0, 0, 0);
            acc[mi][1] = __builtin_amdgcn_mfma_f32_16x16x32_bf16(af, bf1, acc[mi][1], 0, 0, 0);
        }
    }
#pragma unroll
    for (int mi = 0; mi < 4; ++mi) {
        const int c0 = mi * 16 + quad * 4;
        const float4 s4 = *(const float4*)&P[OFF_A0S + c0];
        const float4 o4 = *(const float4*)&P[OFF_A0O + c0];
        const float ss[4] = {s4.x, s4.y, s4.z, s4.w};
        const float oo[4] = {o4.x, o4.y, o4.z, o4.w};
#pragma unroll
        for (int ni = 0; ni < 2; ++ni) {
            const int w = n0w + ni * 16 + l16;
            ushort4 rr; u16* rp = (u16*)&rr;
#pragma unroll
            for (int r = 0; r < 4; ++r) {
                float y = fmaf(acc[mi][ni][r], ss[r], oo[r]);
                float alv = ldin(al0, ((u32)(c0 + r) * 32 + t) * 128 + w, f32);
                rp[r] = f2bf((y >= 0.f) ? y : alv * y);
            }
            *(ushort4*)&g0[((u32)(n * 32 + t) * 128 + w) * 64 + c0] = rr;
        }
    }
}

// ---------------- MFMA tconv0 (K=9 taps) + BN0b(+bt0) -> L0 f32 (LDS-free) ----------------
__global__ __launch_bounds__(256) void k_tconv0(const u16* __restrict__ WTAg, const float* __restrict__ P,
                                                const u16* __restrict__ g0, float* __restrict__ L0)
{
    const int t = blockIdx.x, n = blockIdx.y;
    const int tid = threadIdx.x;
    const int kmin = (t < 4) ? (4 - t) : 0;
    const int kmax = (t > 27) ? (35 - t) : 8;
    const int wv = tid >> 6, lane = tid & 63, l16 = lane & 15, quad = lane >> 4;
    const int n0w = wv * 32;

    f32x4 acc[4][2];
#pragma unroll
    for (int mi = 0; mi < 4; ++mi) { acc[mi][0] = (f32x4){0,0,0,0}; acc[mi][1] = (f32x4){0,0,0,0}; }

    for (int k = kmin; k <= kmax; ++k) {
        const u16* Wb = WTAg + (u32)k * 4096u;                           // [o][i]
        const u16* Bb = g0 + ((u32)(n * 32 + (t + k - 4)) * 128u) * 64u; // [v][i]
#pragma unroll
        for (int ks = 0; ks < 2; ++ks) {
            const int k0 = ks * 32 + quad * 8;
            bf16x8 bf0 = *(const bf16x8*)&Bb[(u32)(n0w + l16) * 64u + k0];
            bf16x8 bf1 = *(const bf16x8*)&Bb[(u32)(n0w + 16 + l16) * 64u + k0];
#pragma unroll
            for (int mi = 0; mi < 4; ++mi) {
                bf16x8 af = *(const bf16x8*)&Wb[(u32)(mi * 16 + l16) * 64u + k0];
                acc[mi][0] = __builtin_amdgcn_mfma_f32_16x16x32_bf16(af, bf0, acc[mi][0], 0, 0, 0);
                acc[mi][1] = __builtin_amdgcn_mfma_f32_16x16x32_bf16(af, bf1, acc[mi][1], 0, 0, 0);
            }
        }
    }
#pragma unroll
    for (int mi = 0; mi < 4; ++mi) {
        const int ob = mi * 16 + quad * 4;
        const float4 s4 = *(const float4*)&P[OFF_B0S + ob];
        const float4 o4 = *(const float4*)&P[OFF_B0O + ob];
        const float ss[4] = {s4.x, s4.y, s4.z, s4.w};
        const float oo[4] = {o4.x, o4.y, o4.z, o4.w};
#pragma unroll
        for (int ni = 0; ni < 2; ++ni) {
            const int v = n0w + ni * 16 + l16;
#pragma unroll
            for (int r = 0; r < 4; ++r)
                L0[((u32)(n * 64 + ob + r) * 32 + t) * 128 + v] = fmaf(acc[mi][ni][r], ss[r], oo[r]);
        }
    }
}

// ---------------- pw1 + graph1(w=0) + BN1a + PReLU -> g1p, reordered contraction ----------------
__global__ __launch_bounds__(256) void k_pw1(const void* __restrict__ a, const void* __restrict__ imp1,
                                             const void* __restrict__ al1, const float* __restrict__ P,
                                             const float* __restrict__ L0, float* __restrict__ g1p,
                                             const int* __restrict__ flagp)
{
    __shared__ float amv[V_];
    __shared__ float xr[CO_];
    __shared__ float Ssh;
    const int f32 = *flagp;
    const int t = blockIdx.x, n = blockIdx.y;
    const int tid = threadIdx.x;

    if (tid < V_) {
        float av = ldin(a, (((u32)n * T_ + t) * V_ + tid) * V_ + 0u, f32)
                 * ldin(imp1, (u32)tid * V_ + 0u, f32);
        amv[tid] = av;
    }
    __syncthreads();
    if (tid < 64) {                                    // S = sum_v amv[v] (wave-0 butterfly)
        float s = amv[tid] + amv[tid + 64];
#pragma unroll
        for (int m = 1; m < 64; m <<= 1) s += __shfl_xor(s, m);
        if (tid == 0) Ssh = s;
    }
    const int c = tid >> 2, sub = tid & 3;
    const float* Lrow = L0 + (u32)n * (CO_ * T_ * V_) + (u32)c * (T_ * V_) + (u32)t * V_ + sub * 32;
    float p = 0.f;
#pragma unroll
    for (int j = 0; j < 32; j += 4) {
        float4 x = *(const float4*)(Lrow + j);
        float4 m = *(const float4*)&amv[sub * 32 + j];
        p = fmaf(x.x, m.x, p); p = fmaf(x.y, m.y, p);
        p = fmaf(x.z, m.z, p); p = fmaf(x.w, m.w, p);
    }
    p += __shfl_xor(p, 1);
    p += __shfl_xor(p, 2);
    if (sub == 0) xr[c] = p;
    __syncthreads();
    if (tid < CO_) {
        const int o = tid;
        float y = P[OFF_BW1 + o] * Ssh;
        for (int cc = 0; cc < CO_; ++cc)
            y = fmaf(xr[cc], P[OFF_W1 + cc * CO_ + o], y);
        y = fmaf(y, P[OFF_A1S + o], P[OFF_A1O + o]);
        float alv = ldin(al1, ((u32)o * T_ + t) * V_ + 0u, f32);
        y = (y >= 0.f) ? y : alv * y;
        g1p[((u32)n * CO_ + o) * T_ + t] = y;
    }
}

// ---------------- temporal conv 1 (v=0) + BN1b(+bt1) + residual + transpose-out ----------------
__global__ __launch_bounds__(256) void k_tconv1(const void* __restrict__ wt1, const float* __restrict__ P,
                                                const float* __restrict__ g1p, const float* __restrict__ L0,
                                                void* __restrict__ out, const int* __restrict__ flagp)
{
    __shared__ float gl[CO_][40];                  // cols 0..3 and 36..39 are zero pads
    const int f32 = *flagp;
    const int n = blockIdx.x;
    const int tid = threadIdx.x;
    for (int e = tid; e < 512; e += 256) {         // zero pads
        int i = e >> 3, p = e & 7;
        gl[i][(p < 4) ? p : (p + 32)] = 0.f;
    }
    for (int e = tid; e < 2048; e += 256) {        // data
        int i = e >> 5, tt = e & 31;
        gl[i][tt + 4] = g1p[(u32)n * 2048u + (u32)i * 32u + tt];
    }
    __syncthreads();
    const int o = tid & 63, tq = tid >> 6, t0 = tq * 8;
    float acc[8];
#pragma unroll
    for (int j = 0; j < 8; ++j) acc[j] = 0.f;
    for (int i = 0; i < CO_; ++i) {
        float win[16];
#pragma unroll
        for (int m = 0; m < 16; m += 4) *(float4*)&win[m] = *(const float4*)&gl[i][t0 + m];
#pragma unroll
        for (int k = 0; k < KT_; ++k) {
            float wv = ldin(wt1, ((u32)(k * CO_ + i)) * CO_ + o, f32);
#pragma unroll
            for (int j = 0; j < 8; ++j) acc[j] = fmaf(win[j + k], wv, acc[j]);
        }
    }
    const float s1 = P[OFF_B1S + o], o1 = P[OFF_B1O + o];
#pragma unroll
    for (int j = 0; j < 8; ++j) {
        const int t = t0 + j;
        float y = fmaf(acc[j], s1, o1);
        y += L0[(u32)n * (CO_ * T_ * V_) + (u32)o * (T_ * V_) + (u32)t * V_ + 0];
        const u32 oi = ((u32)n * T_ + t) * CO_ + o;
        if (f32) ((float*)out)[oi] = y;
        else     ((u16*)out)[oi]   = f2bf(y);
    }
}

__global__ void k_fail(u16* out, int nel) {
    int i = blockIdx.x * 256 + threadIdx.x;
    if (i < nel) out[i] = 0x7f80; // +inf marker: ws too small
}

extern "C" void kernel_launch(void* const* d_in, const int* in_sizes, int n_in,
                              void* d_out, int out_size, void* d_ws, size_t ws_size,
                              hipStream_t stream)
{
    const void* xin  = d_in[0];
    const void* bin  = d_in[1];
    const void* cin2 = d_in[2];
    const void* a    = d_in[3];
    const void* dbn_g = d_in[4];
    const void* dbn_b = d_in[5];
    const void* dbn_m = d_in[6];
    const void* dbn_v = d_in[7];
    const void* w0  = d_in[8];
    const void* bw0 = d_in[9];
    const void* imp0 = d_in[10];
    const void* g0a = d_in[11];
    const void* b0a = d_in[12];
    const void* m0a = d_in[13];
    const void* v0a = d_in[14];
    const void* al0 = d_in[15];
    const void* wt0 = d_in[16];
    const void* bt0 = d_in[17];
    const void* g0b = d_in[18];
    const void* b0b = d_in[19];
    const void* m0b = d_in[20];
    const void* v0b = d_in[21];
    const void* w1  = d_in[22];
    const void* bw1 = d_in[23];
    const void* imp1 = d_in[24];
    const void* g1a = d_in[25];
    const void* b1a = d_in[26];
    const void* m1a = d_in[27];
    const void* v1a = d_in[28];
    const void* al1 = d_in[29];
    const void* wt1 = d_in[30];
    const void* bt1 = d_in[31];
    const void* g1b = d_in[32];
    const void* b1b = d_in[33];
    const void* m1b = d_in[34];
    const void* v1b = d_in[35];

    if (ws_size < (size_t)B_END) {
        k_fail<<<(out_size + 255) / 256, 256, 0, stream>>>((u16*)d_out, out_size);
        return;
    }
    char* w = (char*)d_ws;
    float* P    = (float*)(w + B_P);
    int*   flg  = (int*)(w + B_FLAG);
    u16*   W0A  = (u16*)(w + B_W0A);
    u16*   WTA  = (u16*)(w + B_WTA);
    u16*   h0   = (u16*)(w + B_H0);
    u16*   g0   = (u16*)(w + B_G0);
    float* L0   = (float*)(w + B_L0);
    float* g1p  = (float*)(w + B_G1P);
    u16*   Xp   = (u16*)(w + B_XP2);

    k_detect<<<1, 64, 0, stream>>>(a, flg);
    k_prep<<<(PREP_TOTAL + 255) / 256, 256, 0, stream>>>(
        dbn_g, dbn_b, dbn_m, dbn_v, w0, bw0, g0a, b0a, m0a, v0a,
        bt0, g0b, b0b, m0b, v0b, w1, bw1, g1a, b1a, m1a, v1a,
        bt1, g1b, b1b, m1b, v1b, wt0, P, W0A, WTA, flg);

    dim3 grid(T_, N_);
    k_bnx   <<<dim3(32, 9, 32), 256, 0, stream>>>(xin, bin, cin2, P, Xp, flg);
    k_pw0   <<<dim3(T_, N_, 2), 256, 0, stream>>>(Xp, W0A, h0);
    k_graph0<<<grid, 256, 0, stream>>>(a, imp0, al0, P, h0, g0, flg);
    k_tconv0<<<grid, 256, 0, stream>>>(WTA, P, g0, L0);
    k_pw1   <<<grid, 256, 0, stream>>>(a, imp1, al1, P, L0, g1p, flg);
    k_tconv1<<<dim3(N_), 256, 0, stream>>>(wt1, P, g1p, L0, d_out, flg);
}

// Round 7
// 487.464 us; speedup vs baseline: 1.0426x; 1.0426x over previous
//
#include <hip/hip_runtime.h>
#include <hip/hip_bf16.h>

typedef unsigned short u16;
typedef unsigned int   u32;

#define N_   32
#define T_   32
#define V_   128
#define CIN_ 264
#define CO_  64
#define KT_  9
#define EPS_ 1e-3f

// ---- param table (float offsets inside ws) ----
#define OFF_DBN_S 0          // 33792
#define OFF_DBN_O 33792      // 33792
#define OFF_W0    67584      // 264*64 (f32 copy, unused by mfma path; harmless)
#define OFF_BW0   84480      // 64
#define OFF_A0S   84544
#define OFF_A0O   84608
#define OFF_B0S   84672      // includes bt0 fold
#define OFF_B0O   84736
#define OFF_W1    84800      // 64*64 f32 (pw1)
#define OFF_BW1   88896
#define OFF_A1S   88960
#define OFF_A1O   89024
#define OFF_B1S   89088      // includes bt1 fold
#define OFF_B1O   89152
#define PREP_TOTAL 110464    // + W0A (64*288) + WTA (9*64*64)

// ---- ws byte layout (Xp eliminated by the fused k_pwf) ----
#define B_P    0
#define B_FLAG 360448
#define B_W0A  360512                    // bf16 64 x 288  (36864 B)
#define B_WTA  397440                    // bf16 9 x 64 x 64 (73728 B)
#define B_H0   524288                    // bf16 [n][c][t][v]  16 MB
#define B_G0   (B_H0 + 16777216)         // bf16 [n][t][v][i]  16 MB
#define B_L0   (B_G0 + 16777216)         // f32  [n][c][t][v]  32 MB
#define B_G1P  (B_L0 + 33554432)         // f32  [n][c][t]     256 KB
#define B_END  (B_G1P + 262144)

typedef short bf16x8 __attribute__((ext_vector_type(8)));
typedef float f32x4  __attribute__((ext_vector_type(4)));

__device__ __forceinline__ float bf2f(u16 u) { return __uint_as_float(((u32)u) << 16); }
__device__ __forceinline__ u16 f2bf(float f) {
    u32 x = __float_as_uint(f);
    return (u16)((x + 0x7fffu + ((x >> 16) & 1u)) >> 16);
}
__device__ __forceinline__ float ldin(const void* p, u32 i, int f32) {
    return f32 ? ((const float*)p)[i] : bf2f(((const u16*)p)[i]);
}
// LDS transpose swizzle (row-keyed XOR of the in-row byte offset).
// key m = (row>>3)&7 -> 16B-granular offset; 4 quads reading 4 consecutive
// 8-row stripes land in 4 disjoint bank-octet sets -> transposed scalar
// reads are ~2-way (free). Same map as the proven k_graph0 pattern.
__device__ __forceinline__ u32 swzv(u32 row) {
    u32 m = (row >> 3) & 7u;
    return (m << 4) ^ ((m & 3u) << 5);
}

// ---------------- dtype detect (bf16 vs f32 input buffers) ----------------
__global__ void k_detect(const void* a, int* flag) {
    if (threadIdx.x == 0 && blockIdx.x == 0) {
        const u16* p = (const u16*)a;
        int cnt = 0;
        for (int i = 0; i < 64; ++i) {
            float v = bf2f(p[2 * i]);
            if (v >= 0.f && v <= 1.0f) ++cnt;
        }
        *flag = (cnt >= 56) ? 0 : 1;
    }
}

// ---------------- param prep: BN folds + bf16 MFMA weight layouts ----------------
__global__ void k_prep(const void* dbn_g, const void* dbn_b, const void* dbn_m, const void* dbn_v,
                       const void* w0, const void* bw0,
                       const void* g0a, const void* b0a, const void* m0a, const void* v0a,
                       const void* bt0, const void* g0b, const void* b0b, const void* m0b, const void* v0b,
                       const void* w1, const void* bw1,
                       const void* g1a, const void* b1a, const void* m1a, const void* v1a,
                       const void* bt1, const void* g1b, const void* b1b, const void* m1b, const void* v1b,
                       const void* wt0,
                       float* P, u16* W0A, u16* WTA, const int* flagp)
{
    const int f32 = *flagp;
    int i = blockIdx.x * 256 + threadIdx.x;
    if (i < 33792) {
        float s = ldin(dbn_g, i, f32) * rsqrtf(ldin(dbn_v, i, f32) + EPS_);
        P[OFF_DBN_S + i] = s;
        P[OFF_DBN_O + i] = ldin(dbn_b, i, f32) - ldin(dbn_m, i, f32) * s;
    } else if (i < 50688) { int j = i - 33792; P[OFF_W0 + j] = ldin(w0, j, f32); }
    else if (i < 50752) { int j = i - 50688; P[OFF_BW0 + j] = ldin(bw0, j, f32); }
    else if (i < 50816) { int j = i - 50752;
        float s = ldin(g0a, j, f32) * rsqrtf(ldin(v0a, j, f32) + EPS_);
        P[OFF_A0S + j] = s; P[OFF_A0O + j] = ldin(b0a, j, f32) - ldin(m0a, j, f32) * s;
    } else if (i < 50880) { int j = i - 50816;
        float s = ldin(g0b, j, f32) * rsqrtf(ldin(v0b, j, f32) + EPS_);
        P[OFF_B0S + j] = s; P[OFF_B0O + j] = (ldin(bt0, j, f32) - ldin(m0b, j, f32)) * s + ldin(b0b, j, f32);
    } else if (i < 54976) { int j = i - 50880; P[OFF_W1 + j] = ldin(w1, j, f32); }
    else if (i < 55040) { int j = i - 54976; P[OFF_BW1 + j] = ldin(bw1, j, f32); }
    else if (i < 55104) { int j = i - 55040;
        float s = ldin(g1a, j, f32) * rsqrtf(ldin(v1a, j, f32) + EPS_);
        P[OFF_A1S + j] = s; P[OFF_A1O + j] = ldin(b1a, j, f32) - ldin(m1a, j, f32) * s;
    } else if (i < 55168) { int j = i - 55104;
        float s = ldin(g1b, j, f32) * rsqrtf(ldin(v1b, j, f32) + EPS_);
        P[OFF_B1S + j] = s; P[OFF_B1O + j] = (ldin(bt1, j, f32) - ldin(m1b, j, f32)) * s + ldin(b1b, j, f32);
    } else if (i < 73600) {      // W0A[c][288]: w0^T, row 264 = bw0 (bias trick), 265.. = 0
        int j = i - 55168; int c = j / 288, ci = j - c * 288;
        float val = (ci < 264) ? ldin(w0, (u32)ci * 64 + c, f32)
                  : ((ci == 264) ? ldin(bw0, c, f32) : 0.f);
        W0A[j] = f2bf(val);
    } else if (i < 110464) {     // WTA[k][o][i] = wt0[k][0][i][o]
        int j = i - 73600; int k = j >> 12, rem = j & 4095, o = rem >> 6, ii = rem & 63;
        WTA[j] = f2bf(ldin(wt0, ((u32)(k * 64 + ii)) * 64 + o, f32));
    }
}

// ---------------- FUSED BN+concat+permute gather + MFMA pw0 -> h0 ----------------
// Per (t2, n, vh): build swizzled LDS tile XT[c2=0..287][vvloc=0..63] bf16 directly from the
// raw inputs (the flat-reinterp scramble L = c2*4096 + t2*128 + vh*64 + vvloc maps, for fixed c2,
// to 64 CONSECUTIVE source elements -> coalesced reads). Rows 264..287 hold the bias-1.0 row and
// zeros so the MFMA K-loop is 9 uniform steps. Then D[v][c] = XT^T . W0A^T with A-fragments read
// transposed from LDS (swizzle -> ~2-way, free) and B-fragments from L2-hot W0A.
// Replaces k_bnx + k_pw0: kills the 69MB Xp round-trip and its 64B-scatter writes.
__global__ __launch_bounds__(256) void k_pwf(const void* __restrict__ xin, const void* __restrict__ bin,
                                             const void* __restrict__ cin2, const float* __restrict__ P,
                                             const u16* __restrict__ W0Ag, u16* __restrict__ h0,
                                             const int* __restrict__ flagp)
{
    __shared__ __align__(16) u16 tile[288 * 64];   // 36864 B, [c2][vvloc], byte ^= swzv(c2)
    const int f32 = *flagp;
    const int t2 = blockIdx.x, n = blockIdx.y, vh = blockIdx.z;
    const int tid = threadIdx.x;

    // rows 264..287: row 264 = 1.0 (bias col), rows 265..287 = 0
    for (int e = tid; e < 192; e += 256) {
        int row = 264 + (e >> 3), chunk = e & 7;
        u32 fill = (row == 264) ? 0x3F803F80u : 0u;
        uint4 z = make_uint4(fill, fill, fill, fill);
        u32 byte = (u32)row * 128u + (((u32)chunk * 16u) ^ swzv((u32)row));
        *(uint4*)((char*)tile + byte) = z;
    }
    // rows 0..263: gather 8 consecutive vv per item (cc stays a multiple of 8; the only
    // segment straddle is cc==256 -> 4 from b + 4 from c)
    for (int e = tid; e < 2112; e += 256) {
        int c2 = e >> 3, vv0 = (e & 7) << 3;
        u32 L = (u32)c2 * 4096u + (u32)(t2 * 128 + vh * 64 + vv0);
        u32 vs = L / 8448u;
        u32 r  = L - vs * 8448u;
        u32 ts = r / 264u;
        u32 cc = r - ts * 264u;
        u32 base = ((u32)n * 32u + ts) * 128u + vs;
        u32 ch = vs * 264u + cc;
        float v8[8];
        if (f32) {
            float4 a0, a1;
            if (cc < 256u) {
                const float* sp = (const float*)xin + (size_t)base * 256u + cc;
                a0 = *(const float4*)sp; a1 = *(const float4*)(sp + 4);
            } else {
                a0 = *(const float4*)((const float*)bin  + (size_t)base * 4u);
                a1 = *(const float4*)((const float*)cin2 + (size_t)base * 4u);
            }
            v8[0] = a0.x; v8[1] = a0.y; v8[2] = a0.z; v8[3] = a0.w;
            v8[4] = a1.x; v8[5] = a1.y; v8[6] = a1.z; v8[7] = a1.w;
        } else {
            __align__(16) u16 up[8];
            if (cc < 256u) {
                *(uint4*)up = *(const uint4*)((const u16*)xin + (size_t)base * 256u + cc);
            } else {
                *(ushort4*)&up[0] = *(const ushort4*)((const u16*)bin  + (size_t)base * 4u);
                *(ushort4*)&up[4] = *(const ushort4*)((const u16*)cin2 + (size_t)base * 4u);
            }
#pragma unroll
            for (int j = 0; j < 8; ++j) v8[j] = bf2f(up[j]);
        }
        const float4 s0 = *(const float4*)&P[OFF_DBN_S + ch];
        const float4 s1 = *(const float4*)&P[OFF_DBN_S + ch + 4];
        const float4 o0 = *(const float4*)&P[OFF_DBN_O + ch];
        const float4 o1 = *(const float4*)&P[OFF_DBN_O + ch + 4];
        __align__(16) u16 pk[8];
        pk[0] = f2bf(fmaf(v8[0], s0.x, o0.x));
        pk[1] = f2bf(fmaf(v8[1], s0.y, o0.y));
        pk[2] = f2bf(fmaf(v8[2], s0.z, o0.z));
        pk[3] = f2bf(fmaf(v8[3], s0.w, o0.w));
        pk[4] = f2bf(fmaf(v8[4], s1.x, o1.x));
        pk[5] = f2bf(fmaf(v8[5], s1.y, o1.y));
        pk[6] = f2bf(fmaf(v8[6], s1.z, o1.z));
        pk[7] = f2bf(fmaf(v8[7], s1.w, o1.w));
        u32 byte = (u32)c2 * 128u + (((u32)vv0 * 2u) ^ swzv((u32)c2));
        *(uint4*)((char*)tile + byte) = *(uint4*)pk;
    }
    __syncthreads();

    const int wv = tid >> 6, lane = tid & 63, l16 = lane & 15, quad = lane >> 4;
    f32x4 acc[4];
#pragma unroll
    for (int i = 0; i < 4; ++i) acc[i] = (f32x4){0.f, 0.f, 0.f, 0.f};

#pragma unroll
    for (int ks = 0; ks < 9; ++ks) {               // k = 0..287 (264 real + bias@264 + zeros)
        const int k0 = ks * 32 + quad * 8;
        const u32 xr = swzv((u32)k0);              // constant over the 8-row stripe k0..k0+7
        const u32 cb = ((u32)(wv * 16 + l16) * 2u) ^ xr;
        bf16x8 af;
#pragma unroll
        for (int j = 0; j < 8; ++j)
            af[j] = (short)*(const u16*)((const char*)tile + (u32)(k0 + j) * 128u + cb);
#pragma unroll
        for (int ni = 0; ni < 4; ++ni) {
            bf16x8 bf = *(const bf16x8*)&W0Ag[(u32)(ni * 16 + l16) * 288 + k0];
            acc[ni] = __builtin_amdgcn_mfma_f32_16x16x32_bf16(af, bf, acc[ni], 0, 0, 0);
        }
    }
    const int v = vh * 64 + wv * 16 + quad * 4;
#pragma unroll
    for (int ni = 0; ni < 4; ++ni) {
        int c = ni * 16 + l16;
        ushort4 rr; u16* rp = (u16*)&rr;
#pragma unroll
        for (int r = 0; r < 4; ++r) rp[r] = f2bf(acc[ni][r]);
        *(ushort4*)&h0[((u32)(n * 64 + c) * 32 + t2) * 128 + v] = rr;
    }
}

// ---------------- MFMA graph0, FUSED a*imp transpose + BN0a + PReLU -> g0[n][t][v][i] ----------------
__global__ __launch_bounds__(256) void k_graph0(const void* __restrict__ a, const void* __restrict__ imp0,
                                                const void* __restrict__ al0, const float* __restrict__ P,
                                                const u16* __restrict__ h0, u16* __restrict__ g0,
                                                const int* __restrict__ flagp)
{
    __shared__ __align__(16) u16 tile[128 * 128];  // 32 KB, [v][w] with byte ^= swzv(v)
    const int f32 = *flagp;
    const int t = blockIdx.x, n = blockIdx.y;
    const int tid = threadIdx.x;
    const u32 abase = (((u32)n * 32u + (u32)t) * 128u) * 128u;

    for (int e = tid; e < 2048; e += 256) {
        int v = e >> 4, w0 = (e & 15) << 3;
        float vals[8];
        if (f32) {
            const float* ap = (const float*)a + abase + (u32)v * 128u + w0;
            const float* ip = (const float*)imp0 + (u32)v * 128u + w0;
            float4 x0 = *(const float4*)ap, x1 = *(const float4*)(ap + 4);
            float4 i0 = *(const float4*)ip, i1 = *(const float4*)(ip + 4);
            vals[0] = x0.x * i0.x; vals[1] = x0.y * i0.y; vals[2] = x0.z * i0.z; vals[3] = x0.w * i0.w;
            vals[4] = x1.x * i1.x; vals[5] = x1.y * i1.y; vals[6] = x1.z * i1.z; vals[7] = x1.w * i1.w;
        } else {
            uint4 xu = *(const uint4*)((const u16*)a + abase + (u32)v * 128u + w0);
            uint4 iu = *(const uint4*)((const u16*)imp0 + (u32)v * 128u + w0);
            const u16* xp = (const u16*)&xu; const u16* ip = (const u16*)&iu;
#pragma unroll
            for (int j = 0; j < 8; ++j) vals[j] = bf2f(xp[j]) * bf2f(ip[j]);
        }
        __align__(16) u16 pk[8];
#pragma unroll
        for (int j = 0; j < 8; ++j) pk[j] = f2bf(vals[j]);
        u32 byte = (u32)v * 256u + (((u32)w0 * 2u) ^ swzv((u32)v));
        *(uint4*)((char*)tile + byte) = *(uint4*)pk;
    }
    __syncthreads();

    const int wv = tid >> 6, lane = tid & 63, l16 = lane & 15, quad = lane >> 4;
    const int n0w = wv * 32;
    const u16* Hb = h0 + ((u32)n * 2048u + (u32)t) * 128u;          // + c*4096 + v

    f32x4 acc[4][2];
#pragma unroll
    for (int mi = 0; mi < 4; ++mi) { acc[mi][0] = (f32x4){0,0,0,0}; acc[mi][1] = (f32x4){0,0,0,0}; }
#pragma unroll
    for (int ks = 0; ks < 4; ++ks) {
        const int k0 = ks * 32 + quad * 8;
        const u32 xr = swzv((u32)k0);
        const u32 wb0 = (u32)(n0w + l16) * 2u;
        const u32 wb1 = (u32)(n0w + 16 + l16) * 2u;
        bf16x8 bf0, bf1;
#pragma unroll
        for (int j = 0; j < 8; ++j) {
            const u32 rb = (u32)(k0 + j) * 256u;
            bf0[j] = (short)*(const u16*)((const char*)tile + rb + (wb0 ^ xr));
            bf1[j] = (short)*(const u16*)((const char*)tile + rb + (wb1 ^ xr));
        }
#pragma unroll
        for (int mi = 0; mi < 4; ++mi) {
            bf16x8 af = *(const bf16x8*)&Hb[(u32)(mi * 16 + l16) * 4096u + k0];
            acc[mi][0] = __builtin_amdgcn_mfma_f32_16x16x32_bf16(af, bf0, acc[mi][0], 0, 0, 0);
            acc[mi][1] = __builtin_amdgcn_mfma_f32_16x16x32_bf16(af, bf1, acc[mi][1], 0, 0, 0);
        }
    }
#pragma unroll
    for (int mi = 0; mi < 4; ++mi) {
        const int c0 = mi * 16 + quad * 4;
        const float4 s4 = *(const float4*)&P[OFF_A0S + c0];
        const float4 o4 = *(const float4*)&P[OFF_A0O + c0];
        const float ss[4] = {s4.x, s4.y, s4.z, s4.w};
        const float oo[4] = {o4.x, o4.y, o4.z, o4.w};
#pragma unroll
        for (int ni = 0; ni < 2; ++ni) {
            const int w = n0w + ni * 16 + l16;
            ushort4 rr; u16* rp = (u16*)&rr;
#pragma unroll
            for (int r = 0; r < 4; ++r) {
                float y = fmaf(acc[mi][ni][r], ss[r], oo[r]);
                float alv = ldin(al0, ((u32)(c0 + r) * 32 + t) * 128 + w, f32);
                rp[r] = f2bf((y >= 0.f) ? y : alv * y);
            }
            *(ushort4*)&g0[((u32)(n * 32 + t) * 128 + w) * 64 + c0] = rr;
        }
    }
}

// ---------------- MFMA tconv0 (K=9 taps) + BN0b(+bt0) -> L0 f32 (LDS-free) ----------------
__global__ __launch_bounds__(256) void k_tconv0(const u16* __restrict__ WTAg, const float* __restrict__ P,
                                                const u16* __restrict__ g0, float* __restrict__ L0)
{
    const int t = blockIdx.x, n = blockIdx.y;
    const int tid = threadIdx.x;
    const int kmin = (t < 4) ? (4 - t) : 0;
    const int kmax = (t > 27) ? (35 - t) : 8;
    const int wv = tid >> 6, lane = tid & 63, l16 = lane & 15, quad = lane >> 4;
    const int n0w = wv * 32;

    f32x4 acc[4][2];
#pragma unroll
    for (int mi = 0; mi < 4; ++mi) { acc[mi][0] = (f32x4){0,0,0,0}; acc[mi][1] = (f32x4){0,0,0,0}; }

    for (int k = kmin; k <= kmax; ++k) {
        const u16* Wb = WTAg + (u32)k * 4096u;                           // [o][i]
        const u16* Bb = g0 + ((u32)(n * 32 + (t + k - 4)) * 128u) * 64u; // [v][i]
#pragma unroll
        for (int ks = 0; ks < 2; ++ks) {
            const int k0 = ks * 32 + quad * 8;
            bf16x8 bf0 = *(const bf16x8*)&Bb[(u32)(n0w + l16) * 64u + k0];
            bf16x8 bf1 = *(const bf16x8*)&Bb[(u32)(n0w + 16 + l16) * 64u + k0];
#pragma unroll
            for (int mi = 0; mi < 4; ++mi) {
                bf16x8 af = *(const bf16x8*)&Wb[(u32)(mi * 16 + l16) * 64u + k0];
                acc[mi][0] = __builtin_amdgcn_mfma_f32_16x16x32_bf16(af, bf0, acc[mi][0], 0, 0, 0);
                acc[mi][1] = __builtin_amdgcn_mfma_f32_16x16x32_bf16(af, bf1, acc[mi][1], 0, 0, 0);
            }
        }
    }
#pragma unroll
    for (int mi = 0; mi < 4; ++mi) {
        const int ob = mi * 16 + quad * 4;
        const float4 s4 = *(const float4*)&P[OFF_B0S + ob];
        const float4 o4 = *(const float4*)&P[OFF_B0O + ob];
        const float ss[4] = {s4.x, s4.y, s4.z, s4.w};
        const float oo[4] = {o4.x, o4.y, o4.z, o4.w};
#pragma unroll
        for (int ni = 0; ni < 2; ++ni) {
            const int v = n0w + ni * 16 + l16;
#pragma unroll
            for (int r = 0; r < 4; ++r)
                L0[((u32)(n * 64 + ob + r) * 32 + t) * 128 + v] = fmaf(acc[mi][ni][r], ss[r], oo[r]);
        }
    }
}

// ---------------- pw1 + graph1(w=0) + BN1a + PReLU -> g1p, reordered contraction ----------------
__global__ __launch_bounds__(256) void k_pw1(const void* __restrict__ a, const void* __restrict__ imp1,
                                             const void* __restrict__ al1, const float* __restrict__ P,
                                             const float* __restrict__ L0, float* __restrict__ g1p,
                                             const int* __restrict__ flagp)
{
    __shared__ float amv[V_];
    __shared__ float xr[CO_];
    __shared__ float Ssh;
    const int f32 = *flagp;
    const int t = blockIdx.x, n = blockIdx.y;
    const int tid = threadIdx.x;

    if (tid < V_) {
        float av = ldin(a, (((u32)n * T_ + t) * V_ + tid) * V_ + 0u, f32)
                 * ldin(imp1, (u32)tid * V_ + 0u, f32);
        amv[tid] = av;
    }
    __syncthreads();
    if (tid < 64) {                                    // S = sum_v amv[v] (wave-0 butterfly)
        float s = amv[tid] + amv[tid + 64];
#pragma unroll
        for (int m = 1; m < 64; m <<= 1) s += __shfl_xor(s, m);
        if (tid == 0) Ssh = s;
    }
    const int c = tid >> 2, sub = tid & 3;
    const float* Lrow = L0 + (u32)n * (CO_ * T_ * V_) + (u32)c * (T_ * V_) + (u32)t * V_ + sub * 32;
    float p = 0.f;
#pragma unroll
    for (int j = 0; j < 32; j += 4) {
        float4 x = *(const float4*)(Lrow + j);
        float4 m = *(const float4*)&amv[sub * 32 + j];
        p = fmaf(x.x, m.x, p); p = fmaf(x.y, m.y, p);
        p = fmaf(x.z, m.z, p); p = fmaf(x.w, m.w, p);
    }
    p += __shfl_xor(p, 1);
    p += __shfl_xor(p, 2);
    if (sub == 0) xr[c] = p;
    __syncthreads();
    if (tid < CO_) {
        const int o = tid;
        float y = P[OFF_BW1 + o] * Ssh;
        for (int cc = 0; cc < CO_; ++cc)
            y = fmaf(xr[cc], P[OFF_W1 + cc * CO_ + o], y);
        y = fmaf(y, P[OFF_A1S + o], P[OFF_A1O + o]);
        float alv = ldin(al1, ((u32)o * T_ + t) * V_ + 0u, f32);
        y = (y >= 0.f) ? y : alv * y;
        g1p[((u32)n * CO_ + o) * T_ + t] = y;
    }
}

// ---------------- temporal conv 1 (v=0) + BN1b(+bt1) + residual + transpose-out ----------------
__global__ __launch_bounds__(256) void k_tconv1(const void* __restrict__ wt1, const float* __restrict__ P,
                                                const float* __restrict__ g1p, const float* __restrict__ L0,
                                                void* __restrict__ out, const int* __restrict__ flagp)
{
    __shared__ float gl[CO_][40];                  // cols 0..3 and 36..39 are zero pads
    const int f32 = *flagp;
    const int n = blockIdx.x;
    const int tid = threadIdx.x;
    for (int e = tid; e < 512; e += 256) {         // zero pads
        int i = e >> 3, p = e & 7;
        gl[i][(p < 4) ? p : (p + 32)] = 0.f;
    }
    for (int e = tid; e < 2048; e += 256) {        // data
        int i = e >> 5, tt = e & 31;
        gl[i][tt + 4] = g1p[(u32)n * 2048u + (u32)i * 32u + tt];
    }
    __syncthreads();
    const int o = tid & 63, tq = tid >> 6, t0 = tq * 8;
    float acc[8];
#pragma unroll
    for (int j = 0; j < 8; ++j) acc[j] = 0.f;
    for (int i = 0; i < CO_; ++i) {
        float win[16];
#pragma unroll
        for (int m = 0; m < 16; m += 4) *(float4*)&win[m] = *(const float4*)&gl[i][t0 + m];
#pragma unroll
        for (int k = 0; k < KT_; ++k) {
            float wv = ldin(wt1, ((u32)(k * CO_ + i)) * CO_ + o, f32);
#pragma unroll
            for (int j = 0; j < 8; ++j) acc[j] = fmaf(win[j + k], wv, acc[j]);
        }
    }
    const float s1 = P[OFF_B1S + o], o1 = P[OFF_B1O + o];
#pragma unroll
    for (int j = 0; j < 8; ++j) {
        const int t = t0 + j;
        float y = fmaf(acc[j], s1, o1);
        y += L0[(u32)n * (CO_ * T_ * V_) + (u32)o * (T_ * V_) + (u32)t * V_ + 0];
        const u32 oi = ((u32)n * T_ + t) * CO_ + o;
        if (f32) ((float*)out)[oi] = y;
        else     ((u16*)out)[oi]   = f2bf(y);
    }
}

__global__ void k_fail(u16* out, int nel) {
    int i = blockIdx.x * 256 + threadIdx.x;
    if (i < nel) out[i] = 0x7f80; // +inf marker: ws too small
}

extern "C" void kernel_launch(void* const* d_in, const int* in_sizes, int n_in,
                              void* d_out, int out_size, void* d_ws, size_t ws_size,
                              hipStream_t stream)
{
    const void* xin  = d_in[0];
    const void* bin  = d_in[1];
    const void* cin2 = d_in[2];
    const void* a    = d_in[3];
    const void* dbn_g = d_in[4];
    const void* dbn_b = d_in[5];
    const void* dbn_m = d_in[6];
    const void* dbn_v = d_in[7];
    const void* w0  = d_in[8];
    const void* bw0 = d_in[9];
    const void* imp0 = d_in[10];
    const void* g0a = d_in[11];
    const void* b0a = d_in[12];
    const void* m0a = d_in[13];
    const void* v0a = d_in[14];
    const void* al0 = d_in[15];
    const void* wt0 = d_in[16];
    const void* bt0 = d_in[17];
    const void* g0b = d_in[18];
    const void* b0b = d_in[19];
    const void* m0b = d_in[20];
    const void* v0b = d_in[21];
    const void* w1  = d_in[22];
    const void* bw1 = d_in[23];
    const void* imp1 = d_in[24];
    const void* g1a = d_in[25];
    const void* b1a = d_in[26];
    const void* m1a = d_in[27];
    const void* v1a = d_in[28];
    const void* al1 = d_in[29];
    const void* wt1 = d_in[30];
    const void* bt1 = d_in[31];
    const void* g1b = d_in[32];
    const void* b1b = d_in[33];
    const void* m1b = d_in[34];
    const void* v1b = d_in[35];

    if (ws_size < (size_t)B_END) {
        k_fail<<<(out_size + 255) / 256, 256, 0, stream>>>((u16*)d_out, out_size);
        return;
    }
    char* w = (char*)d_ws;
    float* P    = (float*)(w + B_P);
    int*   flg  = (int*)(w + B_FLAG);
    u16*   W0A  = (u16*)(w + B_W0A);
    u16*   WTA  = (u16*)(w + B_WTA);
    u16*   h0   = (u16*)(w + B_H0);
    u16*   g0   = (u16*)(w + B_G0);
    float* L0   = (float*)(w + B_L0);
    float* g1p  = (float*)(w + B_G1P);

    k_detect<<<1, 64, 0, stream>>>(a, flg);
    k_prep<<<(PREP_TOTAL + 255) / 256, 256, 0, stream>>>(
        dbn_g, dbn_b, dbn_m, dbn_v, w0, bw0, g0a, b0a, m0a, v0a,
        bt0, g0b, b0b, m0b, v0b, w1, bw1, g1a, b1a, m1a, v1a,
        bt1, g1b, b1b, m1b, v1b, wt0, P, W0A, WTA, flg);

    dim3 grid(T_, N_);
    k_pwf   <<<dim3(T_, N_, 2), 256, 0, stream>>>(xin, bin, cin2, P, W0A, h0, flg);
    k_graph0<<<grid, 256, 0, stream>>>(a, imp0, al0, P, h0, g0, flg);
    k_tconv0<<<grid, 256, 0, stream>>>(WTA, P, g0, L0);
    k_pw1   <<<grid, 256, 0, stream>>>(a, imp1, al1, P, L0, g1p, flg);
    k_tconv1<<<dim3(N_), 256, 0, stream>>>(wt1, P, g1p, L0, d_out, flg);
}